// Round 2
// baseline (151.705 us; speedup 1.0000x reference)
//
#include <hip/hip_runtime.h>
#include <stdint.h>

typedef unsigned int u32;
typedef unsigned short u16;
typedef float f32x4 __attribute__((ext_vector_type(4)));
typedef __fp16 h16x2 __attribute__((ext_vector_type(2)));   // cvt_pkrtz native type
typedef _Float16 f16x8 __attribute__((ext_vector_type(8)));
typedef float f4u __attribute__((ext_vector_type(4), aligned(4)));  // 4B-aligned vec load

#define NB   8
#define CIN  256
#define HH   64
#define WW   64
#define HW   4096
#define COUT 256
#define NPX  128   // pixels per block (2 output rows)
#define BSTR 264   // u16 per Bs row (256 + 8 pad; 528B = 33*16B)

__device__ __forceinline__ u32 pkh(float lo, float hi) {
  h16x2 h = __builtin_amdgcn_cvt_pkrtz(lo, hi);   // v_cvt_pkrtz_f16_f32, 1 instr
  return __builtin_bit_cast(u32, h);
}
union HU { u32 u; h16x2 h; };

// ---- prep_all: blocks 0..2047 transpose x -> xT (fp16 NHWC); rest weights ----
// W2f frag layout: frag = (kk*8+cc)*16 + tile; element: lane*8+j ;
// co = (tile>>2)*64 + (tile&3)*16 + (lane&15); c = cc*32 + (lane>>4)*8 + j.
__global__ __launch_bounds__(256) void prep_all(const float* __restrict__ x,
                                                const float* __restrict__ wgt,
                                                u32* __restrict__ xT,
                                                u32* __restrict__ W2f32) {
  int b = blockIdx.x;
  int t = threadIdx.x;
  if (b < 2048) {
    __shared__ __align__(16) u32 tile[16][132];
    int n = b >> 8, hw0 = (b & 255) << 4;
    int hwq = (t & 3) << 2;          // 0,4,8,12
    int cp0 = t >> 2;                // 0..63
    const float* xb = x + (size_t)n * CIN * HW + hw0 + hwq;
#pragma unroll
    for (int it = 0; it < 2; ++it) {
      int cp = (it << 6) + cp0;      // 0..127
      int c = cp << 1;
      f4u v0 = *(const f4u*)(xb + (size_t)c * HW);
      f4u v1 = *(const f4u*)(xb + (size_t)(c + 1) * HW);
      tile[hwq + 0][cp] = pkh(v0.x, v1.x);
      tile[hwq + 1][cp] = pkh(v0.y, v1.y);
      tile[hwq + 2][cp] = pkh(v0.z, v1.z);
      tile[hwq + 3][cp] = pkh(v0.w, v1.w);
    }
    __syncthreads();
    u32* outp = xT + ((size_t)(n * HW + hw0)) * 128;
    int cq = t & 31, hb = t >> 5;    // cq: uint4 col 0..31, hb: row 0..7
#pragma unroll
    for (int it = 0; it < 2; ++it) {
      int hwl = (it << 3) + hb;
      uint4 v = *(const uint4*)&tile[hwl][cq << 2];   // ds_read_b128, 16B-aligned
      *(uint4*)(outp + (size_t)hwl * 128 + (cq << 2)) = v;  // 512B/half-wave
    }
  } else {
    // weights: thread = (co, c-pair); reads 18 consecutive floats
    int tt = (b - 2048) * 256 + t;   // 32768 total
    int cp = tt & 127, co = tt >> 7;
    int c = cp << 1;
    const float* p = wgt + ((size_t)co * CIN + c) * 9;
    f4u q0 = *(const f4u*)(p + 0);
    f4u q1 = *(const f4u*)(p + 4);
    f4u q2 = *(const f4u*)(p + 8);
    f4u q3 = *(const f4u*)(p + 12);
    float e16 = p[16], e17 = p[17];
    float a0[9], a1[9];
    a0[0]=q0.x; a0[1]=q0.y; a0[2]=q0.z; a0[3]=q0.w;
    a0[4]=q1.x; a0[5]=q1.y; a0[6]=q1.z; a0[7]=q1.w; a0[8]=q2.x;
    a1[0]=q2.y; a1[1]=q2.z; a1[2]=q2.w;
    a1[3]=q3.x; a1[4]=q3.y; a1[5]=q3.z; a1[6]=q3.w; a1[7]=e16; a1[8]=e17;
    int cc = c >> 5;
    int j = (c >> 1) & 3;
    int lane = (co & 15) | (((c >> 3) & 3) << 4);
    int tile_ = ((co >> 6) << 2) | ((co >> 4) & 3);
#pragma unroll
    for (int kk = 0; kk < 9; ++kk) {
      int frag = (kk * 8 + cc) * 16 + tile_;
      W2f32[(size_t)frag * 256 + lane * 4 + j] = pkh(a0[kk], a1[kk]);
    }
  }
}

// ---- main: 256 blocks x 1024 threads; block = 256 Cout x 128 px (2 rows) ----
// 16 waves: coT = w&3 (64 Cout), pxH = (w>>2)&1 (64 px), pr = w>>3 (K parity).
// vs r1: B-frag redundancy 8x -> 4x (LDS reads halved); af issued BEFORE
// gathers so MFMA waits vmcnt(4) not vmcnt(0); epilogue b128 XOR-swizzled.
__global__ __launch_bounds__(1024, 4) void dcn_main(
    const float* __restrict__ offset, const float* __restrict__ mask,
    const float* __restrict__ bias, const u16* __restrict__ xT,
    const u16* __restrict__ W2f, float* __restrict__ out) {
  __shared__ __align__(16) u16 Bs[2][NPX * BSTR];  // 2 x 67.6 KB
  __shared__ __align__(8)  uint2 swl[1152];        // (kk,p): 4 corner wts, fp16 pairs
  __shared__ __align__(8)  ushort4 sol[1152];      // (kk,p): 4 corner position indices

  int bid = blockIdx.x;      // 256 blocks = 1/CU
  int n = bid & 7;           // XCD swizzle: XCD k serves n==k -> 2MB xT slice in L2
  int hp = bid >> 3;         // ho-pair 0..31
  int t = threadIdx.x;
  int lane = t & 63;
  int w = t >> 6;            // wave 0..15

  // 1) sample precompute: 9 taps x 128 px
  for (int i = t; i < 1152; i += 1024) {
    int kk = i >> 7, p = i & 127;
    int ky = kk / 3, kx = kk - ky * 3;
    int sp = (hp << 7) + p;             // = ho*64 + (p&63)
    int ho = (hp << 1) + (p >> 6);
    float dy = offset[(((size_t)n * 18 + kk * 2 + 0) << 12) + sp];
    float dx = offset[(((size_t)n * 18 + kk * 2 + 1) << 12) + sp];
    float m  = mask  [(((size_t)n * 9  + kk) << 12) + sp];
    float ys = (float)(ky + ho - 1) + dy;
    float xs = (float)(kx + (p & 63) - 1) + dx;
    float y0f = floorf(ys), x0f = floorf(xs);
    float fy = ys - y0f, fx = xs - x0f;
    int y0 = (int)y0f, x0 = (int)x0f;
    int y1 = y0 + 1, x1 = x0 + 1;
    float vy0 = (y0 >= 0 && y0 < HH) ? 1.f : 0.f;
    float vy1 = (y1 >= 0 && y1 < HH) ? 1.f : 0.f;
    float vx0 = (x0 >= 0 && x0 < WW) ? 1.f : 0.f;
    float vx1 = (x1 >= 0 && x1 < WW) ? 1.f : 0.f;
    float w0 = (1.f - fy) * (1.f - fx) * m * vy0 * vx0;
    float w1 = (1.f - fy) * fx * m * vy0 * vx1;
    float w2 = fy * (1.f - fx) * m * vy1 * vx0;
    float w3 = fy * fx * m * vy1 * vx1;
    int iy0 = min(max(y0, 0), HH - 1), iy1 = min(max(y1, 0), HH - 1);
    int ix0 = min(max(x0, 0), WW - 1), ix1 = min(max(x1, 0), WW - 1);
    ushort4 pv;
    pv.x = (u16)((iy0 << 6) + ix0);
    pv.y = (u16)((iy0 << 6) + ix1);
    pv.z = (u16)((iy1 << 6) + ix0);
    pv.w = (u16)((iy1 << 6) + ix1);
    swl[i] = make_uint2(pkh(w0, w1), pkh(w2, w3));
    sol[i] = pv;
  }
  __syncthreads();

  f32x4 acc[4][4];
#pragma unroll
  for (int a = 0; a < 4; ++a)
#pragma unroll
    for (int b2 = 0; b2 < 4; ++b2) acc[a][b2] = {0.f, 0.f, 0.f, 0.f};

  const char* xTn = (const char*)xT + ((size_t)n * HW << 9);
  int ml = lane & 15, q = lane >> 4;
  int hw32 = t >> 5;     // half-wave id 0..31: builds px = g*32 + hw32
  int l32 = t & 31;
  int coT = w & 3, pxH = (w >> 2) & 1, pr = w >> 3;
  int tile0 = coT << 2;                 // 4 consecutive co-tiles = 64 Cout
  const char* bch = xTn + (l32 << 4);

// accumulate one register-resident corner (8 v_fma_mix_f32)
#define CMB(G, WT) do {                                                \
    float wt = (WT);                                                   \
    HU h0, h1, h2, h3;                                                 \
    h0.u = (G).x; h1.u = (G).y; h2.u = (G).z; h3.u = (G).w;            \
    s0 = __builtin_fmaf((float)h0.h.x, wt, s0);                        \
    s1 = __builtin_fmaf((float)h0.h.y, wt, s1);                        \
    s2 = __builtin_fmaf((float)h1.h.x, wt, s2);                        \
    s3 = __builtin_fmaf((float)h1.h.y, wt, s3);                        \
    s4 = __builtin_fmaf((float)h2.h.x, wt, s4);                        \
    s5 = __builtin_fmaf((float)h2.h.y, wt, s5);                        \
    s6 = __builtin_fmaf((float)h3.h.x, wt, s6);                        \
    s7 = __builtin_fmaf((float)h3.h.y, wt, s7);                        \
  } while (0)

  // monolithic build for the prologue (tap 0 into buf 0)
  auto build0 = [&](int g) {
    int px = (g << 5) + hw32;
    uint2 wu = swl[px];
    ushort4 pv = sol[px];
    HU ha, hb; ha.u = wu.x; hb.u = wu.y;
    uint4 G0 = *(const uint4*)(bch + ((int)pv.x << 9));
    uint4 G1 = *(const uint4*)(bch + ((int)pv.y << 9));
    uint4 G2 = *(const uint4*)(bch + ((int)pv.z << 9));
    uint4 G3 = *(const uint4*)(bch + ((int)pv.w << 9));
    float s0=0.f,s1=0.f,s2=0.f,s3=0.f,s4=0.f,s5=0.f,s6=0.f,s7=0.f;
    CMB(G0, (float)ha.h.x);
    CMB(G1, (float)ha.h.y);
    CMB(G2, (float)hb.h.x);
    CMB(G3, (float)hb.h.y);
    uint4 pkd;
    pkd.x = pkh(s0, s1); pkd.y = pkh(s2, s3);
    pkd.z = pkh(s4, s5); pkd.w = pkh(s6, s7);
    *(uint4*)((char*)&Bs[0][0] + px * (BSTR * 2) + (l32 << 4)) = pkd;
  };

  auto af_load = [&](int fidx, int mt) {
    return *(const f16x8*)(W2f + (((size_t)((fidx << 4) + tile0 + mt)) << 9) +
                           (lane << 3));
  };

#pragma unroll
  for (int g = 0; g < 4; ++g) build0(g);
  __syncthreads();

#pragma unroll 1
  for (int kk = 0; kk < 9; ++kk) {
    int cur = kk & 1;
    char* Bw = (char*)&Bs[cur ^ 1][0];
    const char* Br = (const char*)&Bs[cur][0];
    int fbase = kk << 3;
#pragma unroll
    for (int g = 0; g < 4; ++g) {
      int px = (g << 5) + hw32;
      int cc = (g << 1) | pr;
      // af first: MFMA then only needs vmcnt(4) (gathers stay in flight)
      f16x8 af0 = af_load(fbase + cc, 0);
      f16x8 af1 = af_load(fbase + cc, 1);
      f16x8 af2 = af_load(fbase + cc, 2);
      f16x8 af3 = af_load(fbase + cc, 3);
      uint4 G0, G1, G2, G3;
      if (kk < 8) {        // EARLY: issue next-tap gathers for this px-group
        ushort4 pv = sol[((kk + 1) << 7) + px];
        G0 = *(const uint4*)(bch + ((int)pv.x << 9));
        G1 = *(const uint4*)(bch + ((int)pv.y << 9));
        G2 = *(const uint4*)(bch + ((int)pv.z << 9));
        G3 = *(const uint4*)(bch + ((int)pv.w << 9));
      }
      // MFMA: 4x4 outer product (af[4] x bq pairs), rows offset by pxH
      {
        int rbase = pxH << 2;
#pragma unroll
        for (int half = 0; half < 2; ++half) {
          f16x8 b0 = *(const f16x8*)(Br +
                  (((rbase + (half << 1) + 0) << 4) + ml) * (BSTR * 2) +
                  (cc << 6) + (q << 4));
          f16x8 b1 = *(const f16x8*)(Br +
                  (((rbase + (half << 1) + 1) << 4) + ml) * (BSTR * 2) +
                  (cc << 6) + (q << 4));
          int n0 = (half << 1), n1 = n0 + 1;
          __builtin_amdgcn_s_setprio(1);
          acc[0][n0] = __builtin_amdgcn_mfma_f32_16x16x32_f16(af0, b0, acc[0][n0], 0, 0, 0);
          acc[0][n1] = __builtin_amdgcn_mfma_f32_16x16x32_f16(af0, b1, acc[0][n1], 0, 0, 0);
          acc[1][n0] = __builtin_amdgcn_mfma_f32_16x16x32_f16(af1, b0, acc[1][n0], 0, 0, 0);
          acc[1][n1] = __builtin_amdgcn_mfma_f32_16x16x32_f16(af1, b1, acc[1][n1], 0, 0, 0);
          acc[2][n0] = __builtin_amdgcn_mfma_f32_16x16x32_f16(af2, b0, acc[2][n0], 0, 0, 0);
          acc[2][n1] = __builtin_amdgcn_mfma_f32_16x16x32_f16(af2, b1, acc[2][n1], 0, 0, 0);
          acc[3][n0] = __builtin_amdgcn_mfma_f32_16x16x32_f16(af3, b0, acc[3][n0], 0, 0, 0);
          acc[3][n1] = __builtin_amdgcn_mfma_f32_16x16x32_f16(af3, b1, acc[3][n1], 0, 0, 0);
          __builtin_amdgcn_s_setprio(0);
        }
      }
      if (kk < 8) {        // LATE: combine (vmcnt satisfied) + LDS write
        uint2 wu = swl[((kk + 1) << 7) + px];
        HU ha, hb; ha.u = wu.x; hb.u = wu.y;
        float s0=0.f,s1=0.f,s2=0.f,s3=0.f,s4=0.f,s5=0.f,s6=0.f,s7=0.f;
        CMB(G0, (float)ha.h.x);
        CMB(G1, (float)ha.h.y);
        CMB(G2, (float)hb.h.x);
        CMB(G3, (float)hb.h.y);
        uint4 pkd;
        pkd.x = pkh(s0, s1); pkd.y = pkh(s2, s3);
        pkd.z = pkh(s4, s5); pkd.w = pkh(s6, s7);
        *(uint4*)(Bw + px * (BSTR * 2) + (l32 << 4)) = pkd;
      }
    }
    __syncthreads();   // all waves done reading Bs[cur] / writing Bs[cur^1]
  }

  // epilogue: pair-reduce parity partials through LDS (reuse Bs as 32768 f32)
  // layout: pid*4096 + lane*64 + (chunk ^ (lane&7))*4 ; XOR keeps 16B chunks
  // aligned and spreads banks (conflict-free b128).
  float* PS = (float*)&Bs[0][0];
  int pid = w & 7;                       // (pxH,coT) pair id shared by pr 0/1
  float* P = PS + pid * 4096 + lane * 64;
  int sw = lane & 7;
  if (pr) {
#pragma unroll
    for (int mt = 0; mt < 4; ++mt)
#pragma unroll
      for (int nt = 0; nt < 4; ++nt)
        *(f32x4*)&P[(((mt << 2) + nt) ^ sw) << 2] = acc[mt][nt];
  }
  __syncthreads();
  if (!pr) {
    // D layout: row = q*4+r (Cout), col = ml (px); m91-verified
    size_t ob = (size_t)n * COUT * HW + ((size_t)hp << 7);
#pragma unroll
    for (int mt = 0; mt < 4; ++mt) {
      int co0 = (coT << 6) + (mt << 4) + (q << 2);
      f4u bv = *(const f4u*)&bias[co0];
#pragma unroll
      for (int nt = 0; nt < 4; ++nt) {
        f32x4 pv = *(const f32x4*)&P[(((mt << 2) + nt) ^ sw) << 2];
        int px = (pxH << 6) + (nt << 4) + ml;
#pragma unroll
        for (int r = 0; r < 4; ++r)
          out[ob + (size_t)(co0 + r) * HW + px] =
              acc[mt][nt][r] + pv[r] + bv[r];
      }
    }
  }
}

extern "C" void kernel_launch(void* const* d_in, const int* in_sizes, int n_in,
                              void* d_out, int out_size, void* d_ws, size_t ws_size,
                              hipStream_t stream) {
  const float* x      = (const float*)d_in[0];
  const float* offset = (const float*)d_in[1];
  const float* mask   = (const float*)d_in[2];
  const float* weight = (const float*)d_in[3];
  const float* bias   = (const float*)d_in[4];
  float* out = (float*)d_out;

  u16* xT  = (u16*)d_ws;                                      // 16 MB fp16
  u16* W2f = (u16*)((char*)d_ws + (size_t)NB * HW * CIN * 2); // +1.18 MB fp16

  prep_all<<<2176, 256, 0, stream>>>(x, weight, (u32*)xT, (u32*)W2f);
  dcn_main<<<256, 1024, 0, stream>>>(offset, mask, bias, xT, W2f, out);
}

// Round 3
// 151.156 us; speedup vs baseline: 1.0036x; 1.0036x over previous
//
#include <hip/hip_runtime.h>
#include <stdint.h>

typedef unsigned int u32;
typedef unsigned short u16;
typedef float f32x4 __attribute__((ext_vector_type(4)));
typedef __fp16 h16x2 __attribute__((ext_vector_type(2)));   // cvt_pkrtz native type
typedef _Float16 f16x8 __attribute__((ext_vector_type(8)));
typedef float f4u __attribute__((ext_vector_type(4), aligned(4)));  // 4B-aligned vec load

#define NB   8
#define CIN  256
#define HH   64
#define WW   64
#define HW   4096
#define COUT 256
#define NPX  64    // pixels per block (1 output row) -- 2 blocks/CU
#define BSTR 264   // u16 per Bs row (256 + 8 pad; 528B = 33*16B)

__device__ __forceinline__ u32 pkh(float lo, float hi) {
  h16x2 h = __builtin_amdgcn_cvt_pkrtz(lo, hi);   // v_cvt_pkrtz_f16_f32, 1 instr
  return __builtin_bit_cast(u32, h);
}
union HU { u32 u; h16x2 h; };

// ---- prep_all: blocks 0..2047 transpose x -> xT (fp16 NHWC); rest weights ----
// W2f frag layout: frag = (kk*8+cc)*16 + tile; element: lane*8+j ;
// co = (tile>>2)*64 + (tile&3)*16 + (lane&15); c = cc*32 + (lane>>4)*8 + j.
__global__ __launch_bounds__(256) void prep_all(const float* __restrict__ x,
                                                const float* __restrict__ wgt,
                                                u32* __restrict__ xT,
                                                u32* __restrict__ W2f32) {
  int b = blockIdx.x;
  int t = threadIdx.x;
  if (b < 2048) {
    __shared__ __align__(16) u32 tile[16][132];
    int n = b >> 8, hw0 = (b & 255) << 4;
    int hwq = (t & 3) << 2;          // 0,4,8,12
    int cp0 = t >> 2;                // 0..63
    const float* xb = x + (size_t)n * CIN * HW + hw0 + hwq;
#pragma unroll
    for (int it = 0; it < 2; ++it) {
      int cp = (it << 6) + cp0;      // 0..127
      int c = cp << 1;
      f4u v0 = *(const f4u*)(xb + (size_t)c * HW);
      f4u v1 = *(const f4u*)(xb + (size_t)(c + 1) * HW);
      tile[hwq + 0][cp] = pkh(v0.x, v1.x);
      tile[hwq + 1][cp] = pkh(v0.y, v1.y);
      tile[hwq + 2][cp] = pkh(v0.z, v1.z);
      tile[hwq + 3][cp] = pkh(v0.w, v1.w);
    }
    __syncthreads();
    u32* outp = xT + ((size_t)(n * HW + hw0)) * 128;
    int cq = t & 31, hb = t >> 5;    // cq: uint4 col 0..31, hb: row 0..7
#pragma unroll
    for (int it = 0; it < 2; ++it) {
      int hwl = (it << 3) + hb;
      uint4 v = *(const uint4*)&tile[hwl][cq << 2];   // ds_read_b128, 16B-aligned
      *(uint4*)(outp + (size_t)hwl * 128 + (cq << 2)) = v;  // 512B/half-wave
    }
  } else {
    // weights: thread = (co, c-pair); reads 18 consecutive floats
    int tt = (b - 2048) * 256 + t;   // 32768 total
    int cp = tt & 127, co = tt >> 7;
    int c = cp << 1;
    const float* p = wgt + ((size_t)co * CIN + c) * 9;
    f4u q0 = *(const f4u*)(p + 0);
    f4u q1 = *(const f4u*)(p + 4);
    f4u q2 = *(const f4u*)(p + 8);
    f4u q3 = *(const f4u*)(p + 12);
    float e16 = p[16], e17 = p[17];
    float a0[9], a1[9];
    a0[0]=q0.x; a0[1]=q0.y; a0[2]=q0.z; a0[3]=q0.w;
    a0[4]=q1.x; a0[5]=q1.y; a0[6]=q1.z; a0[7]=q1.w; a0[8]=q2.x;
    a1[0]=q2.y; a1[1]=q2.z; a1[2]=q2.w;
    a1[3]=q3.x; a1[4]=q3.y; a1[5]=q3.z; a1[6]=q3.w; a1[7]=e16; a1[8]=e17;
    int cc = c >> 5;
    int j = (c >> 1) & 3;
    int lane = (co & 15) | (((c >> 3) & 3) << 4);
    int tile_ = ((co >> 6) << 2) | ((co >> 4) & 3);
#pragma unroll
    for (int kk = 0; kk < 9; ++kk) {
      int frag = (kk * 8 + cc) * 16 + tile_;
      W2f32[(size_t)frag * 256 + lane * 4 + j] = pkh(a0[kk], a1[kk]);
    }
  }
}

// ---- main: 512 blocks x 512 threads; block = 256 Cout x 64 px (1 row) ----
// 2 blocks/CU (75KB LDS each): independent barrier domains overlap the per-tap
// __syncthreads drain that single-block r2 could not hide (all pipes <35%).
// 8 waves: coT = w&3 (64 Cout), pr = w>>2 (K parity). Same per-wave MFMA count.
__global__ __launch_bounds__(512, 4) void dcn_main(
    const float* __restrict__ offset, const float* __restrict__ mask,
    const float* __restrict__ bias, const u16* __restrict__ xT,
    const u16* __restrict__ W2f, float* __restrict__ out) {
  __shared__ __align__(16) u16 Bs[2][NPX * BSTR];  // 2 x 33.8 KB
  __shared__ __align__(8)  uint2 swl[576];         // (kk,p): 4 corner wts, fp16 pairs
  __shared__ __align__(8)  ushort4 sol[576];       // (kk,p): 4 corner position indices

  int bid = blockIdx.x;      // 512 blocks = 2/CU
  int n = bid & 7;           // XCD swizzle: XCD k serves n==k -> 2MB xT slice in L2
  int hp = bid >> 3;         // output row ho = hp, 0..63
  int t = threadIdx.x;
  int lane = t & 63;
  int w = t >> 6;            // wave 0..7

  // 1) sample precompute: 9 taps x 64 px
  for (int i = t; i < 576; i += 512) {
    int kk = i >> 6, p = i & 63;
    int ky = kk / 3, kx = kk - ky * 3;
    int sp = (hp << 6) + p;
    float dy = offset[(((size_t)n * 18 + kk * 2 + 0) << 12) + sp];
    float dx = offset[(((size_t)n * 18 + kk * 2 + 1) << 12) + sp];
    float m  = mask  [(((size_t)n * 9  + kk) << 12) + sp];
    float ys = (float)(ky + hp - 1) + dy;
    float xs = (float)(kx + p - 1) + dx;
    float y0f = floorf(ys), x0f = floorf(xs);
    float fy = ys - y0f, fx = xs - x0f;
    int y0 = (int)y0f, x0 = (int)x0f;
    int y1 = y0 + 1, x1 = x0 + 1;
    float vy0 = (y0 >= 0 && y0 < HH) ? 1.f : 0.f;
    float vy1 = (y1 >= 0 && y1 < HH) ? 1.f : 0.f;
    float vx0 = (x0 >= 0 && x0 < WW) ? 1.f : 0.f;
    float vx1 = (x1 >= 0 && x1 < WW) ? 1.f : 0.f;
    float w0 = (1.f - fy) * (1.f - fx) * m * vy0 * vx0;
    float w1 = (1.f - fy) * fx * m * vy0 * vx1;
    float w2 = fy * (1.f - fx) * m * vy1 * vx0;
    float w3 = fy * fx * m * vy1 * vx1;
    int iy0 = min(max(y0, 0), HH - 1), iy1 = min(max(y1, 0), HH - 1);
    int ix0 = min(max(x0, 0), WW - 1), ix1 = min(max(x1, 0), WW - 1);
    ushort4 pv;
    pv.x = (u16)((iy0 << 6) + ix0);
    pv.y = (u16)((iy0 << 6) + ix1);
    pv.z = (u16)((iy1 << 6) + ix0);
    pv.w = (u16)((iy1 << 6) + ix1);
    swl[i] = make_uint2(pkh(w0, w1), pkh(w2, w3));
    sol[i] = pv;
  }
  __syncthreads();

  f32x4 acc[4][4];
#pragma unroll
  for (int a = 0; a < 4; ++a)
#pragma unroll
    for (int b2 = 0; b2 < 4; ++b2) acc[a][b2] = {0.f, 0.f, 0.f, 0.f};

  const char* xTn = (const char*)xT + ((size_t)n * HW << 9);
  int ml = lane & 15, q = lane >> 4;
  int hw32 = t >> 5;     // half-wave id 0..15: builds px = g*16 + hw32
  int l32 = t & 31;
  int coT = w & 3, pr = w >> 2;
  int tile0 = coT << 2;                 // 4 consecutive co-tiles = 64 Cout
  const char* bch = xTn + (l32 << 4);

// accumulate one register-resident corner (8 v_fma_mix_f32)
#define CMB(G, WT) do {                                                \
    float wt = (WT);                                                   \
    HU h0, h1, h2, h3;                                                 \
    h0.u = (G).x; h1.u = (G).y; h2.u = (G).z; h3.u = (G).w;            \
    s0 = __builtin_fmaf((float)h0.h.x, wt, s0);                        \
    s1 = __builtin_fmaf((float)h0.h.y, wt, s1);                        \
    s2 = __builtin_fmaf((float)h1.h.x, wt, s2);                        \
    s3 = __builtin_fmaf((float)h1.h.y, wt, s3);                        \
    s4 = __builtin_fmaf((float)h2.h.x, wt, s4);                        \
    s5 = __builtin_fmaf((float)h2.h.y, wt, s5);                        \
    s6 = __builtin_fmaf((float)h3.h.x, wt, s6);                        \
    s7 = __builtin_fmaf((float)h3.h.y, wt, s7);                        \
  } while (0)

  // monolithic build for the prologue (tap 0 into buf 0)
  auto build0 = [&](int g) {
    int px = (g << 4) + hw32;
    uint2 wu = swl[px];
    ushort4 pv = sol[px];
    HU ha, hb; ha.u = wu.x; hb.u = wu.y;
    uint4 G0 = *(const uint4*)(bch + ((int)pv.x << 9));
    uint4 G1 = *(const uint4*)(bch + ((int)pv.y << 9));
    uint4 G2 = *(const uint4*)(bch + ((int)pv.z << 9));
    uint4 G3 = *(const uint4*)(bch + ((int)pv.w << 9));
    float s0=0.f,s1=0.f,s2=0.f,s3=0.f,s4=0.f,s5=0.f,s6=0.f,s7=0.f;
    CMB(G0, (float)ha.h.x);
    CMB(G1, (float)ha.h.y);
    CMB(G2, (float)hb.h.x);
    CMB(G3, (float)hb.h.y);
    uint4 pkd;
    pkd.x = pkh(s0, s1); pkd.y = pkh(s2, s3);
    pkd.z = pkh(s4, s5); pkd.w = pkh(s6, s7);
    *(uint4*)((char*)&Bs[0][0] + px * (BSTR * 2) + (l32 << 4)) = pkd;
  };

  auto af_load = [&](int fidx, int mt) {
    return *(const f16x8*)(W2f + (((size_t)((fidx << 4) + tile0 + mt)) << 9) +
                           (lane << 3));
  };

#pragma unroll
  for (int g = 0; g < 4; ++g) build0(g);
  __syncthreads();

#pragma unroll 1
  for (int kk = 0; kk < 9; ++kk) {
    int cur = kk & 1;
    char* Bw = (char*)&Bs[cur ^ 1][0];
    const char* Br = (const char*)&Bs[cur][0];
    int fbase = kk << 3;
#pragma unroll
    for (int g = 0; g < 4; ++g) {
      int px = (g << 4) + hw32;
      int cc = (g << 1) | pr;
      // af first: MFMA then only needs vmcnt(4) (gathers stay in flight)
      f16x8 af0 = af_load(fbase + cc, 0);
      f16x8 af1 = af_load(fbase + cc, 1);
      f16x8 af2 = af_load(fbase + cc, 2);
      f16x8 af3 = af_load(fbase + cc, 3);
      uint4 G0, G1, G2, G3;
      if (kk < 8) {        // EARLY: issue next-tap gathers for this px-group
        ushort4 pv = sol[((kk + 1) << 6) + px];
        G0 = *(const uint4*)(bch + ((int)pv.x << 9));
        G1 = *(const uint4*)(bch + ((int)pv.y << 9));
        G2 = *(const uint4*)(bch + ((int)pv.z << 9));
        G3 = *(const uint4*)(bch + ((int)pv.w << 9));
      }
      // MFMA: 4 af x 4 px-tiles (this wave covers all 64 px of the row)
      {
#pragma unroll
        for (int half = 0; half < 2; ++half) {
          f16x8 b0 = *(const f16x8*)(Br +
                  ((((half << 1) + 0) << 4) + ml) * (BSTR * 2) +
                  (cc << 6) + (q << 4));
          f16x8 b1 = *(const f16x8*)(Br +
                  ((((half << 1) + 1) << 4) + ml) * (BSTR * 2) +
                  (cc << 6) + (q << 4));
          int n0 = (half << 1), n1 = n0 + 1;
          __builtin_amdgcn_s_setprio(1);
          acc[0][n0] = __builtin_amdgcn_mfma_f32_16x16x32_f16(af0, b0, acc[0][n0], 0, 0, 0);
          acc[0][n1] = __builtin_amdgcn_mfma_f32_16x16x32_f16(af0, b1, acc[0][n1], 0, 0, 0);
          acc[1][n0] = __builtin_amdgcn_mfma_f32_16x16x32_f16(af1, b0, acc[1][n0], 0, 0, 0);
          acc[1][n1] = __builtin_amdgcn_mfma_f32_16x16x32_f16(af1, b1, acc[1][n1], 0, 0, 0);
          acc[2][n0] = __builtin_amdgcn_mfma_f32_16x16x32_f16(af2, b0, acc[2][n0], 0, 0, 0);
          acc[2][n1] = __builtin_amdgcn_mfma_f32_16x16x32_f16(af2, b1, acc[2][n1], 0, 0, 0);
          acc[3][n0] = __builtin_amdgcn_mfma_f32_16x16x32_f16(af3, b0, acc[3][n0], 0, 0, 0);
          acc[3][n1] = __builtin_amdgcn_mfma_f32_16x16x32_f16(af3, b1, acc[3][n1], 0, 0, 0);
          __builtin_amdgcn_s_setprio(0);
        }
      }
      if (kk < 8) {        // LATE: combine (vmcnt satisfied) + LDS write
        uint2 wu = swl[((kk + 1) << 6) + px];
        HU ha, hb; ha.u = wu.x; hb.u = wu.y;
        float s0=0.f,s1=0.f,s2=0.f,s3=0.f,s4=0.f,s5=0.f,s6=0.f,s7=0.f;
        CMB(G0, (float)ha.h.x);
        CMB(G1, (float)ha.h.y);
        CMB(G2, (float)hb.h.x);
        CMB(G3, (float)hb.h.y);
        uint4 pkd;
        pkd.x = pkh(s0, s1); pkd.y = pkh(s2, s3);
        pkd.z = pkh(s4, s5); pkd.w = pkh(s6, s7);
        *(uint4*)(Bw + px * (BSTR * 2) + (l32 << 4)) = pkd;
      }
    }
    __syncthreads();   // all waves done reading Bs[cur] / writing Bs[cur^1]
  }

  // epilogue: pair-reduce parity partials through LDS (reuse Bs as f32)
  // layout: pid*4096 + lane*64 + (chunk ^ (lane&7))*4 ; XOR keeps 16B chunks
  // aligned and spreads banks (conflict-free b128). 4 pids x 64KB total.
  float* PS = (float*)&Bs[0][0];
  int pid = w & 3;                       // coT pair id shared by pr 0/1
  float* P = PS + pid * 4096 + lane * 64;
  int sw = lane & 7;
  if (pr) {
#pragma unroll
    for (int mt = 0; mt < 4; ++mt)
#pragma unroll
      for (int nt = 0; nt < 4; ++nt)
        *(f32x4*)&P[(((mt << 2) + nt) ^ sw) << 2] = acc[mt][nt];
  }
  __syncthreads();
  if (!pr) {
    // D layout: row = q*4+r (Cout), col = ml (px); m91-verified
    size_t ob = (size_t)n * COUT * HW + ((size_t)hp << 6);
#pragma unroll
    for (int mt = 0; mt < 4; ++mt) {
      int co0 = (coT << 6) + (mt << 4) + (q << 2);
      f4u bv = *(const f4u*)&bias[co0];
#pragma unroll
      for (int nt = 0; nt < 4; ++nt) {
        f32x4 pv = *(const f32x4*)&P[(((mt << 2) + nt) ^ sw) << 2];
        int px = (nt << 4) + ml;
#pragma unroll
        for (int r = 0; r < 4; ++r)
          out[ob + (size_t)(co0 + r) * HW + px] =
              acc[mt][nt][r] + pv[r] + bv[r];
      }
    }
  }
}

extern "C" void kernel_launch(void* const* d_in, const int* in_sizes, int n_in,
                              void* d_out, int out_size, void* d_ws, size_t ws_size,
                              hipStream_t stream) {
  const float* x      = (const float*)d_in[0];
  const float* offset = (const float*)d_in[1];
  const float* mask   = (const float*)d_in[2];
  const float* weight = (const float*)d_in[3];
  const float* bias   = (const float*)d_in[4];
  float* out = (float*)d_out;

  u16* xT  = (u16*)d_ws;                                      // 16 MB fp16
  u16* W2f = (u16*)((char*)d_ws + (size_t)NB * HW * CIN * 2); // +1.18 MB fp16

  prep_all<<<2176, 256, 0, stream>>>(x, weight, (u32*)xT, (u32*)W2f);
  dcn_main<<<512, 512, 0, stream>>>(offset, mask, bias, xT, W2f, out);
}